// Round 15
// baseline (320.731 us; speedup 1.0000x reference)
//
#include <hip/hip_runtime.h>

// ---------------------------------------------------------------------------
// CMSFlipLinear: y = x @ W^T, W = ternary * per-128-group scales.
// Round 15: i8 path (absmax 0.383). B (weights) now loaded DIRECTLY
// global->VGPR fragments (L2-resident 2 MB band per XCD) -- no LDS staging
// for B. LDS holds only A (16 KiB dbuf = 32 KiB): LDS-read pipe drops
// 192->32 wave-reads/step (2304->384 cyc, no longer co-bottleneck), and
// regs fall to ~100 VGPR + 64 AGPR -> 3 independent blocks/CU (the
// uncorrelated-wave overlap that same-block schedules R5/R8/R14 never got;
// R8/R14 measured full read+mma serialization at 2 waves/SIMD).
// 128x128 tile, BK=128, 4 waves (2x2) of 64x64; single barrier per K-tile
// (R14 transform; A-buffer race proof unchanged); B-frag loads auto-vmcnt.
// Swizzle (XCD owns bcol band, iterates brow; 4 bcols per brow step) keeps
// B in L2 and gives A-strip 4x consecutive reuse. A-stage swizzle geometry
// 0-conflict across 8 rounds. M=8192, N=4096, K=4096.
// ---------------------------------------------------------------------------

typedef int intx4 __attribute__((ext_vector_type(4)));

constexpr int K  = 4096;
constexpr int N  = 4096;
constexpr int NG = 32;   // groups per output row = K/128

__device__ __forceinline__ void gload_lds16(const void* gsrc, void* ldst) {
  const __attribute__((address_space(1))) unsigned* g =
      reinterpret_cast<const __attribute__((address_space(1))) unsigned*>(
          reinterpret_cast<uintptr_t>(gsrc));
  __attribute__((address_space(3))) unsigned* l =
      reinterpret_cast<__attribute__((address_space(3))) unsigned*>(
          reinterpret_cast<uintptr_t>(ldst));
  __builtin_amdgcn_global_load_lds(g, l, 16, 0, 0);
}

// ---- prep 1: x -> i8 with per-row scale ------------------------------------
__global__ __launch_bounds__(256) void quant_x_kernel(const float* __restrict__ x,
                                                      char* __restrict__ q,
                                                      float* __restrict__ sx) {
  const int row = blockIdx.x;
  const int tid = threadIdx.x;
  const float4* xr = reinterpret_cast<const float4*>(x + (long)row * K);
  float4 v[4];
  float am = 0.f;
#pragma unroll
  for (int j = 0; j < 4; ++j) {
    v[j] = xr[tid * 4 + j];
    am = fmaxf(am, fmaxf(fmaxf(fabsf(v[j].x), fabsf(v[j].y)),
                         fmaxf(fabsf(v[j].z), fabsf(v[j].w))));
  }
#pragma unroll
  for (int off = 32; off > 0; off >>= 1)
    am = fmaxf(am, __shfl_xor(am, off));
  __shared__ float wmax[4];
  if ((tid & 63) == 0) wmax[tid >> 6] = am;
  __syncthreads();
  am = fmaxf(fmaxf(wmax[0], wmax[1]), fmaxf(wmax[2], wmax[3]));
  const float inv = am > 0.f ? 127.f / am : 0.f;
  int t[16];
#pragma unroll
  for (int j = 0; j < 4; ++j) {
    t[j * 4 + 0] = (int)rintf(v[j].x * inv);
    t[j * 4 + 1] = (int)rintf(v[j].y * inv);
    t[j * 4 + 2] = (int)rintf(v[j].z * inv);
    t[j * 4 + 3] = (int)rintf(v[j].w * inv);
  }
  int4 o;
  o.x = (t[0] & 255) | ((t[1] & 255) << 8) | ((t[2] & 255) << 16) | ((t[3] & 255) << 24);
  o.y = (t[4] & 255) | ((t[5] & 255) << 8) | ((t[6] & 255) << 16) | ((t[7] & 255) << 24);
  o.z = (t[8] & 255) | ((t[9] & 255) << 8) | ((t[10] & 255) << 16) | ((t[11] & 255) << 24);
  o.w = (t[12] & 255) | ((t[13] & 255) << 8) | ((t[14] & 255) << 16) | ((t[15] & 255) << 24);
  reinterpret_cast<int4*>(q + (long)row * K)[tid] = o;
  if (tid == 0) sx[row] = am * (1.f / 127.f);
}

// ---- prep 2: wq = tern * round(127*s/S_row); sw[row] = S_row/127 -----------
__global__ __launch_bounds__(256) void pack_w_kernel(const int* __restrict__ w,
                                                     const float* __restrict__ s,
                                                     char* __restrict__ o,
                                                     float* __restrict__ sw) {
  const int row = blockIdx.x;
  const int tid = threadIdx.x;
  __shared__ float Ssh;
  if (tid < 64) {
    float v = (tid < NG) ? s[(long)row * NG + tid] : 0.f;
#pragma unroll
    for (int off = 32; off > 0; off >>= 1)
      v = fmaxf(v, __shfl_xor(v, off));
    if (tid == 0) {
      Ssh = v;
      sw[row] = v * (1.f / 127.f);
    }
  }
  __syncthreads();
  const float S = Ssh;
  const int g = tid >> 3;  // 16 weights/thread -> group = tid*16/128
  const int m = (int)rintf(127.f * s[(long)row * NG + g] / S);
  const int4* src = reinterpret_cast<const int4*>(w + (long)row * K + tid * 16);
  int4 a = src[0], b = src[1], c = src[2], d = src[3];
  int4 r;
  r.x = ((a.x * m) & 255) | (((a.y * m) & 255) << 8) |
        (((a.z * m) & 255) << 16) | (((a.w * m) & 255) << 24);
  r.y = ((b.x * m) & 255) | (((b.y * m) & 255) << 8) |
        (((b.z * m) & 255) << 16) | (((b.w * m) & 255) << 24);
  r.z = ((c.x * m) & 255) | (((c.y * m) & 255) << 8) |
        (((c.z * m) & 255) << 16) | (((c.w * m) & 255) << 24);
  r.w = ((d.x * m) & 255) | (((d.y * m) & 255) << 8) |
        (((d.z * m) & 255) << 16) | (((d.w * m) & 255) << 24);
  reinterpret_cast<int4*>(o + (long)row * K)[tid] = r;
}

// ---------------------------------------------------------------------------
// GEMM LDS: A only, dbuf: buf b at b*16384, 128 rows x 128 B. Swizzle:
// byte = row*128 + (slot ^ ((row&7)<<4)) on ds_read AND on the global source
// of the linear-dest global_load_lds (rule #21). 0 conflicts, 8 rounds.
// B fragments: direct global loads (no LDS), full-cacheline use per wave.
// ---------------------------------------------------------------------------

__device__ __forceinline__ intx4 ldfrag(const char* region, int row, int slot) {
  return *reinterpret_cast<const intx4*>(region + row * 128 +
                                         (slot ^ ((row & 7) << 4)));
}

// One staging round: 32 rows x 128 B = 4 KiB (256 thr x 16 B).
__device__ __forceinline__ void stage_round(const char* gmat, char* lregion,
                                            int k0, int rnd, int wid, int l) {
  const int row = rnd * 32 + wid * 8 + (l >> 3);
  const int col = ((l & 7) ^ ((l >> 3) & 7)) << 4;  // inverse-swizzled source
  const char* g = gmat + (long)row * K + k0 + col;
  char* ldst = lregion + rnd * 4096 + wid * 1024;   // + lane*16 by HW
  gload_lds16(g, ldst);
}

#define FENCE asm volatile("" ::: "memory")
#define BAR                       \
  do {                            \
    __builtin_amdgcn_s_barrier(); \
    FENCE;                        \
  } while (0)
#define VMCNT0 asm volatile("s_waitcnt vmcnt(0)" ::: "memory")

// 128x128x128-tile i8 GEMM, 4 waves (2Mx2N), 64x64 out per wave.
// A via LDS dbuf (single barrier/tile); B direct from global (L2-resident).
__global__ __launch_bounds__(256) void gemm_i8(
    const char* __restrict__ A, const char* __restrict__ B,
    const float* __restrict__ SW, const float* __restrict__ SX,
    float* __restrict__ C) {
  __shared__ char lds[32768];  // A double buffer only
  const int tid = threadIdx.x;
  const int wid = tid >> 6, l = tid & 63;
  const int wr = wid >> 1, wc = wid & 1;
  const int rlo = l & 15, kq = l >> 4;

  // Swizzle (2048 blocks, bijective): xcd = wg&7 owns a 4-wide bcol band
  // (B band = 4*128 rows x 4096 B = 2 MB -> L2-resident across all brow
  // steps); idx iterates bcol-minor so each A-strip is reused 4x back-to-back.
  const int wg = blockIdx.x;
  const int xcd = wg & 7;
  const int idx = wg >> 3;  // 0..255
  const long bcol = (long)(xcd * 4 + (idx & 3)) * 128;  // 32 N-tiles
  const long brow = (long)(idx >> 2) * 128;             // 64 M-tiles

  const char* gA = A + brow * K;
  const char* gB = B + (bcol + wc * 64) * K;  // wave's B rows base

  intx4 acc[4][4] = {};
  intx4 af[4], bf[4][2];

  // prologue: stage A tile 0 into buf 0 (4 gloads/thread)
#pragma unroll
  for (int r = 0; r < 4; ++r) stage_round(gA, lds, 0, r, wid, l);

#pragma unroll 1
  for (int t = 0; t < 32; ++t) {
    const int k0 = t << 7;
    const char* a_cur = lds + (t & 1) * 16384;
    VMCNT0;  // A-stage for tile t (issued ~1 tile ago / prologue) landed
    BAR;     // all waves see tile t; all buf^1 reads (tile t-1) retired
    // B fragments for tile t: direct global loads (L2 hits; compiler
    // inserts the vmcnt waits before first use).
#pragma unroll
    for (int nt = 0; nt < 4; ++nt)
#pragma unroll
      for (int ks = 0; ks < 2; ++ks)
        bf[nt][ks] = *reinterpret_cast<const intx4*>(
            gB + (long)(nt * 16 + rlo) * K + k0 + ks * 64 + kq * 16);
    // stage A tile t+1 into buf^1 (safe: issued after BAR)
    if (t < 31) {
      char* a_nxt = lds + ((t + 1) & 1) * 16384;
      const int kn = (t + 1) << 7;
#pragma unroll
      for (int r = 0; r < 4; ++r) stage_round(gA, a_nxt, kn, r, wid, l);
    }
#pragma unroll
    for (int ks = 0; ks < 2; ++ks) {
#pragma unroll
      for (int mi = 0; mi < 4; ++mi)
        af[mi] = ldfrag(a_cur, wr * 64 + mi * 16 + rlo, ks * 64 + kq * 16);
      __builtin_amdgcn_s_setprio(1);
#pragma unroll
      for (int mi = 0; mi < 4; ++mi)
#pragma unroll
        for (int nt = 0; nt < 4; ++nt)
          acc[mi][nt] = __builtin_amdgcn_mfma_i32_16x16x64_i8(
              af[mi], bf[nt][ks], acc[mi][nt], 0, 0, 0);
      __builtin_amdgcn_s_setprio(0);
    }
  }

  // Epilogue: y = acc * SX[row] * SW[col]. col = lane&15, row = kq*4 + r.
  const long crow0 = brow + wr * 64 + kq * 4;
  const long ccol = bcol + wc * 64 + rlo;
  float swn[4];
#pragma unroll
  for (int nt = 0; nt < 4; ++nt) swn[nt] = SW[ccol + nt * 16];
#pragma unroll
  for (int mi = 0; mi < 4; ++mi) {
    const float4 sx4 = *reinterpret_cast<const float4*>(SX + crow0 + mi * 16);
    const float sxr[4] = {sx4.x, sx4.y, sx4.z, sx4.w};
#pragma unroll
    for (int nt = 0; nt < 4; ++nt) {
      float* cp = C + (crow0 + mi * 16) * (long)N + ccol + nt * 16;
#pragma unroll
      for (int r = 0; r < 4; ++r)
        cp[r * N] = (float)acc[mi][nt][r] * sxr[r] * swn[nt];
    }
  }
}

// ---- fallback (only if workspace too small): naive fp32 --------------------
__global__ void fallback_kernel(const float* __restrict__ x,
                                const int* __restrict__ t,
                                const float* __restrict__ s,
                                float* __restrict__ y) {
  int n = blockIdx.x * 256 + threadIdx.x;
  int m = blockIdx.y;
  const int* tr = t + (long)n * K;
  const float* xr = x + (long)m * K;
  float acc = 0.f;
  for (int g = 0; g < K / 128; ++g) {
    float scv = s[n * (K / 128) + g];
    float part = 0.f;
#pragma unroll 4
    for (int k = g * 128; k < g * 128 + 128; ++k)
      part += xr[k] * (float)tr[k];
    acc += part * scv;
  }
  y[(long)m * N + n] = acc;
}

extern "C" void kernel_launch(void* const* d_in, const int* in_sizes, int n_in,
                              void* d_out, int out_size, void* d_ws,
                              size_t ws_size, hipStream_t stream) {
  const float* x = (const float*)d_in[0];
  const int* tern = (const int*)d_in[1];
  const float* scales = (const float*)d_in[2];
  float* out = (float*)d_out;

  const long M = (long)in_sizes[0] / K;  // 8192
  const size_t offW = (size_t)M * K;              // A_i8: 32 MiB
  const size_t offSW = offW + (size_t)N * K;      // W_i8: 16 MiB
  const size_t offSX = offSW + (size_t)N * 4;     // SW f32: 16 KiB
  const size_t need = offSX + (size_t)M * 4;      // SX f32: 32 KiB

  if (ws_size >= need && M == 8192) {
    char* Aq = (char*)d_ws;
    char* Wq = (char*)d_ws + offW;
    float* SW = (float*)((char*)d_ws + offSW);
    float* SX = (float*)((char*)d_ws + offSX);

    quant_x_kernel<<<(unsigned)M, 256, 0, stream>>>(x, Aq, SX);
    pack_w_kernel<<<(unsigned)N, 256, 0, stream>>>(tern, scales, Wq, SW);

    const unsigned nblk = (unsigned)((M / 128) * (N / 128));  // 2048
    gemm_i8<<<nblk, 256, 0, stream>>>(Aq, Wq, SW, SX, out);
  } else {
    dim3 grid(N / 256, (unsigned)M);
    fallback_kernel<<<grid, 256, 0, stream>>>(x, tern, scales, out);
  }
}

// Round 16
// 181.455 us; speedup vs baseline: 1.7676x; 1.7676x over previous
//
#include <hip/hip_runtime.h>

// ---------------------------------------------------------------------------
// CMSFlipLinear: y = x @ W^T, W = ternary * per-128-group scales.
// Round 16: R8 geometry (256x256, BK=128, 8 waves, best measured: 138us)
// restructured ks-MAJOR: 2 phases/tile of {12 ds_reads -> 32 MFMA} instead of
// 4 quadrant-phases. Same 48 fragment VGPRs as R8 (B-per-ks 16 + A-per-ks 32)
// -> occupancy preserved (2 waves/SIMD). Convoy count per tile halves and
// each read burst gets a 653-cyc MFMA shadow (vs 326). Single barrier +
// VMCNT0 per tile (R14-proven race pattern), double-buffered LDS.
// acc = pure-MFMA i32 in AGPRs (spill fix). Swizzle geometry 0-conflict
// across 9 rounds. absmax 0.383 (R8 numerics). M=8192, N=4096, K=4096.
// ---------------------------------------------------------------------------

typedef int intx4 __attribute__((ext_vector_type(4)));

constexpr int K  = 4096;
constexpr int N  = 4096;
constexpr int NG = 32;   // groups per output row = K/128

__device__ __forceinline__ void gload_lds16(const void* gsrc, void* ldst) {
  const __attribute__((address_space(1))) unsigned* g =
      reinterpret_cast<const __attribute__((address_space(1))) unsigned*>(
          reinterpret_cast<uintptr_t>(gsrc));
  __attribute__((address_space(3))) unsigned* l =
      reinterpret_cast<__attribute__((address_space(3))) unsigned*>(
          reinterpret_cast<uintptr_t>(ldst));
  __builtin_amdgcn_global_load_lds(g, l, 16, 0, 0);
}

// ---- prep 1: x -> i8 with per-row scale ------------------------------------
__global__ __launch_bounds__(256) void quant_x_kernel(const float* __restrict__ x,
                                                      char* __restrict__ q,
                                                      float* __restrict__ sx) {
  const int row = blockIdx.x;
  const int tid = threadIdx.x;
  const float4* xr = reinterpret_cast<const float4*>(x + (long)row * K);
  float4 v[4];
  float am = 0.f;
#pragma unroll
  for (int j = 0; j < 4; ++j) {
    v[j] = xr[tid * 4 + j];
    am = fmaxf(am, fmaxf(fmaxf(fabsf(v[j].x), fabsf(v[j].y)),
                         fmaxf(fabsf(v[j].z), fabsf(v[j].w))));
  }
#pragma unroll
  for (int off = 32; off > 0; off >>= 1)
    am = fmaxf(am, __shfl_xor(am, off));
  __shared__ float wmax[4];
  if ((tid & 63) == 0) wmax[tid >> 6] = am;
  __syncthreads();
  am = fmaxf(fmaxf(wmax[0], wmax[1]), fmaxf(wmax[2], wmax[3]));
  const float inv = am > 0.f ? 127.f / am : 0.f;
  int t[16];
#pragma unroll
  for (int j = 0; j < 4; ++j) {
    t[j * 4 + 0] = (int)rintf(v[j].x * inv);
    t[j * 4 + 1] = (int)rintf(v[j].y * inv);
    t[j * 4 + 2] = (int)rintf(v[j].z * inv);
    t[j * 4 + 3] = (int)rintf(v[j].w * inv);
  }
  int4 o;
  o.x = (t[0] & 255) | ((t[1] & 255) << 8) | ((t[2] & 255) << 16) | ((t[3] & 255) << 24);
  o.y = (t[4] & 255) | ((t[5] & 255) << 8) | ((t[6] & 255) << 16) | ((t[7] & 255) << 24);
  o.z = (t[8] & 255) | ((t[9] & 255) << 8) | ((t[10] & 255) << 16) | ((t[11] & 255) << 24);
  o.w = (t[12] & 255) | ((t[13] & 255) << 8) | ((t[14] & 255) << 16) | ((t[15] & 255) << 24);
  reinterpret_cast<int4*>(q + (long)row * K)[tid] = o;
  if (tid == 0) sx[row] = am * (1.f / 127.f);
}

// ---- prep 2: wq = tern * round(127*s/S_row); sw[row] = S_row/127 -----------
__global__ __launch_bounds__(256) void pack_w_kernel(const int* __restrict__ w,
                                                     const float* __restrict__ s,
                                                     char* __restrict__ o,
                                                     float* __restrict__ sw) {
  const int row = blockIdx.x;
  const int tid = threadIdx.x;
  __shared__ float Ssh;
  if (tid < 64) {
    float v = (tid < NG) ? s[(long)row * NG + tid] : 0.f;
#pragma unroll
    for (int off = 32; off > 0; off >>= 1)
      v = fmaxf(v, __shfl_xor(v, off));
    if (tid == 0) {
      Ssh = v;
      sw[row] = v * (1.f / 127.f);
    }
  }
  __syncthreads();
  const float S = Ssh;
  const int g = tid >> 3;  // 16 weights/thread -> group = tid*16/128
  const int m = (int)rintf(127.f * s[(long)row * NG + g] / S);
  const int4* src = reinterpret_cast<const int4*>(w + (long)row * K + tid * 16);
  int4 a = src[0], b = src[1], c = src[2], d = src[3];
  int4 r;
  r.x = ((a.x * m) & 255) | (((a.y * m) & 255) << 8) |
        (((a.z * m) & 255) << 16) | (((a.w * m) & 255) << 24);
  r.y = ((b.x * m) & 255) | (((b.y * m) & 255) << 8) |
        (((b.z * m) & 255) << 16) | (((b.w * m) & 255) << 24);
  r.z = ((c.x * m) & 255) | (((c.y * m) & 255) << 8) |
        (((c.z * m) & 255) << 16) | (((c.w * m) & 255) << 24);
  r.w = ((d.x * m) & 255) | (((d.y * m) & 255) << 8) |
        (((d.z * m) & 255) << 16) | (((d.w * m) & 255) << 24);
  reinterpret_cast<int4*>(o + (long)row * K)[tid] = r;
}

// ---------------------------------------------------------------------------
// GEMM LDS (bytes): buf b at b*65536: A@+0 (32 KiB) | B@+32768 (32 KiB).
// Rows = 128 B. Swizzle: byte = row*128 + (slot ^ ((row&7)<<4)), applied on
// ds_read AND on the global source of the linear-dest global_load_lds
// (rule #21). 16-rows x 8-slot read geometry: 0 conflicts, 9 rounds.
// ---------------------------------------------------------------------------

__device__ __forceinline__ intx4 ldfrag(const char* region, int row, int slot) {
  return *reinterpret_cast<const intx4*>(region + row * 128 +
                                         (slot ^ ((row & 7) << 4)));
}

// Stage one half-tile (128 rows x 128 B = 16 KiB): 2 loads/thread (512 thr).
__device__ __forceinline__ void stage_half(const char* gmat, char* lregion,
                                           int k0, int h, int wid, int l) {
#pragma unroll
  for (int load = 0; load < 2; ++load) {
    const int row = h * 128 + load * 64 + wid * 8 + (l >> 3);
    const int col = ((l & 7) ^ ((l >> 3) & 7)) << 4;
    const char* g = gmat + (long)row * K + k0 + col;
    char* ldst = lregion + h * 16384 + load * 8192 + wid * 1024;  // +lane*16B HW
    gload_lds16(g, ldst);
  }
}

#define FENCE asm volatile("" ::: "memory")
#define BAR                       \
  do {                            \
    __builtin_amdgcn_s_barrier(); \
    FENCE;                        \
  } while (0)
#define VMCNT0 asm volatile("s_waitcnt vmcnt(0)" ::: "memory")

// 256x256x128-tile i8 GEMM, 8 waves (2Mx4N), 128x64 out per wave.
// ks-major: 2 phases/tile of {B-ks(4)+A-ks(8) reads -> 32 MFMA}.
__global__ __launch_bounds__(512) void gemm8p(
    const char* __restrict__ A, const char* __restrict__ B,
    const float* __restrict__ SW, const float* __restrict__ SX,
    float* __restrict__ C) {
  __shared__ char lds[131072];  // 128 KiB
  const int tid = threadIdx.x;
  const int wid = tid >> 6, l = tid & 63;
  const int wr = wid >> 2, wc = wid & 3;
  const int rlo = l & 15, kq = l >> 4;

  // T1: bijective XCD swizzle (512 blocks, 512%8==0) — R8's (FETCH-optimal)
  const int wg = blockIdx.x;
  const int swz = (wg & 7) * 64 + (wg >> 3);
  const long brow = (long)(swz >> 4) * 256;  // 32 M-tiles
  const long bcol = (long)(swz & 15) * 256;  // 16 N-tiles

  const char* gA = A + brow * K;
  const char* gB = B + bcol * K;

  intx4 acc[8][4] = {};

  // prologue: stage tile 0 into buf 0 (8 gloads/thread)
  stage_half(gA, lds, 0, 0, wid, l);
  stage_half(gA, lds, 0, 1, wid, l);
  stage_half(gB, lds + 32768, 0, 0, wid, l);
  stage_half(gB, lds + 32768, 0, 1, wid, l);

#pragma unroll 1
  for (int t = 0; t < 32; ++t) {
    const int curoff = (t & 1) * 65536;
    const char* a_cur = lds + curoff;
    const char* b_cur = lds + curoff + 32768;
    VMCNT0;  // tile t's 8 stage loads (issued ~1 tile ago) landed, this wave
    BAR;     // -> landed for all waves; all waves' buf^1 reads retired
    if (t < 31) {
      const int nxtoff = ((t + 1) & 1) * 65536;
      const int kn = (t + 1) << 7;
      char* a_nxt = lds + nxtoff;
      char* b_nxt = lds + nxtoff + 32768;
      stage_half(gA, a_nxt, kn, 0, wid, l);
      stage_half(gA, a_nxt, kn, 1, wid, l);
      stage_half(gB, b_nxt, kn, 0, wid, l);
      stage_half(gB, b_nxt, kn, 1, wid, l);
    }
    // ks-major: two fat phases. 12 reads then 32 MFMA each; compiler's
    // counted lgkm lets the first mma start as soon as its operands land.
#pragma unroll
    for (int ks = 0; ks < 2; ++ks) {
      intx4 bf[4], af[8];
#pragma unroll
      for (int nt = 0; nt < 4; ++nt)
        bf[nt] = ldfrag(b_cur, wc * 64 + nt * 16 + rlo, ks * 64 + kq * 16);
#pragma unroll
      for (int mi = 0; mi < 8; ++mi)
        af[mi] = ldfrag(a_cur, wr * 128 + mi * 16 + rlo, ks * 64 + kq * 16);
      __builtin_amdgcn_s_setprio(1);
#pragma unroll
      for (int j = 0; j < 32; ++j) {
        const int mi = j >> 2, nt = j & 3;
        acc[mi][nt] = __builtin_amdgcn_mfma_i32_16x16x64_i8(
            af[mi], bf[nt], acc[mi][nt], 0, 0, 0);
      }
      __builtin_amdgcn_s_setprio(0);
    }
  }

  // Epilogue: y = acc * SX[row] * SW[col]. col = lane&15, row = kq*4 + r.
  const long crow0 = brow + wr * 128 + kq * 4;
  const long ccol = bcol + wc * 64 + rlo;
  float swn[4];
#pragma unroll
  for (int nt = 0; nt < 4; ++nt) swn[nt] = SW[ccol + nt * 16];
#pragma unroll
  for (int mi = 0; mi < 8; ++mi) {
    const float4 sx4 = *reinterpret_cast<const float4*>(SX + crow0 + mi * 16);
    const float sxr[4] = {sx4.x, sx4.y, sx4.z, sx4.w};
#pragma unroll
    for (int nt = 0; nt < 4; ++nt) {
      float* cp = C + (crow0 + mi * 16) * (long)N + ccol + nt * 16;
#pragma unroll
      for (int r = 0; r < 4; ++r)
        cp[r * N] = (float)acc[mi][nt][r] * sxr[r] * swn[nt];
    }
  }
}

// ---- fallback (only if workspace too small): naive fp32 --------------------
__global__ void fallback_kernel(const float* __restrict__ x,
                                const int* __restrict__ t,
                                const float* __restrict__ s,
                                float* __restrict__ y) {
  int n = blockIdx.x * 256 + threadIdx.x;
  int m = blockIdx.y;
  const int* tr = t + (long)n * K;
  const float* xr = x + (long)m * K;
  float acc = 0.f;
  for (int g = 0; g < K / 128; ++g) {
    float scv = s[n * (K / 128) + g];
    float part = 0.f;
#pragma unroll 4
    for (int k = g * 128; k < g * 128 + 128; ++k)
      part += xr[k] * (float)tr[k];
    acc += part * scv;
  }
  y[(long)m * N + n] = acc;
}

extern "C" void kernel_launch(void* const* d_in, const int* in_sizes, int n_in,
                              void* d_out, int out_size, void* d_ws,
                              size_t ws_size, hipStream_t stream) {
  const float* x = (const float*)d_in[0];
  const int* tern = (const int*)d_in[1];
  const float* scales = (const float*)d_in[2];
  float* out = (float*)d_out;

  const long M = (long)in_sizes[0] / K;  // 8192
  const size_t offW = (size_t)M * K;              // A_i8: 32 MiB
  const size_t offSW = offW + (size_t)N * K;      // W_i8: 16 MiB
  const size_t offSX = offSW + (size_t)N * 4;     // SW f32: 16 KiB
  const size_t need = offSX + (size_t)M * 4;      // SX f32: 32 KiB

  if (ws_size >= need && M == 8192) {
    char* Aq = (char*)d_ws;
    char* Wq = (char*)d_ws + offW;
    float* SW = (float*)((char*)d_ws + offSW);
    float* SX = (float*)((char*)d_ws + offSX);

    quant_x_kernel<<<(unsigned)M, 256, 0, stream>>>(x, Aq, SX);
    pack_w_kernel<<<(unsigned)N, 256, 0, stream>>>(tern, scales, Wq, SW);

    const unsigned nblk = (unsigned)((M / 256) * (N / 256));  // 512
    gemm8p<<<nblk, 512, 0, stream>>>(Aq, Wq, SW, SX, out);
  } else {
    dim3 grid(N / 256, (unsigned)M);
    fallback_kernel<<<grid, 256, 0, stream>>>(x, tern, scales, out);
  }
}